// Round 3
// baseline (64.801 us; speedup 1.0000x reference)
//
#include <hip/hip_runtime.h>

// EnergyPool2d: N=16, C=64, H=W=128, 3x3 windows stride 1 -> Ho=Wo=126.
// +1 at first-argmax flat index, -1 at first-argmin flat index per window.
// Separable formulation: horizontal 1x3 argmax/argmin per (row, col), then
// vertical first-occurrence scan over 3 row-stats == row-major tie-break.

#define HH 128
#define WW 128
#define HO 126
#define WO 126
#define PLANE (HH * WW)   // 16384
#define NPLANES (16 * 64) // 1024
#define BLOCK 1024
#define GT 128            // threads per group (one output column each)
#define GROUPS (BLOCK / GT)
#define ROWS_PER_G 16     // groups 0..6: 16 window rows; group 7: 14

// Horizontal stat for one row at column t: first-occurrence argmax/argmin over
// x[t], x[t+1], x[t+2]. 'base' is the flat index of (row, t); A/a are full
// flat indices of the chosen element.
__device__ __forceinline__ void hstat(const float* __restrict__ p, int base,
                                      float& M, int& A, float& m, int& a) {
    const float v0 = p[0], v1 = p[1], v2 = p[2];
    M = v0; A = base;
    if (v1 > M) { M = v1; A = base + 1; }
    if (v2 > M) { M = v2; A = base + 2; }
    m = v0; a = base;
    if (v1 < m) { m = v1; a = base + 1; }
    if (v2 < m) { m = v2; a = base + 2; }
}

template <int NWR>
__device__ __forceinline__ void run_rows(const float* __restrict__ p, int base,
                                         int* __restrict__ cnt) {
    float M[3], m[3];
    int A[3], a[3];
    hstat(p, base, M[0], A[0], m[0], a[0]); p += WW; base += WW;
    hstat(p, base, M[1], A[1], m[1], a[1]); p += WW; base += WW;
#pragma unroll
    for (int r = 0; r < NWR; ++r) {
        const int s0 = r % 3, s1 = (r + 1) % 3, s2 = (r + 2) % 3;
        hstat(p, base, M[s2], A[s2], m[s2], a[s2]); p += WW; base += WW;
        // Vertical first-occurrence over rows r, r+1, r+2 (strict >/<).
        float WM = M[s0]; int wf = A[s0];
        if (M[s1] > WM) { WM = M[s1]; wf = A[s1]; }
        if (M[s2] > WM) { WM = M[s2]; wf = A[s2]; }
        atomicAdd(&cnt[wf], 1);
        float Wm = m[s0]; int wg = a[s0];
        if (m[s1] < Wm) { Wm = m[s1]; wg = a[s1]; }
        if (m[s2] < Wm) { Wm = m[s2]; wg = a[s2]; }
        atomicAdd(&cnt[wg], -1);
    }
}

__global__ __launch_bounds__(BLOCK, 8)
void energy_pool2d_kernel(const float* __restrict__ x, float* __restrict__ out) {
    __shared__ int cnt[PLANE]; // 64 KB

    const int tid = threadIdx.x;
    const int plane = blockIdx.x;
    const float* __restrict__ xp = x + (size_t)plane * PLANE;

    // Zero the LDS count plane.
    int4* c4 = (int4*)cnt;
#pragma unroll
    for (int i = 0; i < PLANE / 4 / BLOCK; ++i)
        c4[tid + i * BLOCK] = make_int4(0, 0, 0, 0);
    __syncthreads();

    const int g = tid >> 7;        // group id (wave-uniform)
    const int t = tid & (GT - 1);  // output column owned by this thread
    if (t < WO) {
        const int wr0 = g * ROWS_PER_G;
        const int base = wr0 * WW + t;
        const float* __restrict__ p = xp + base;
        if (g < GROUPS - 1)
            run_rows<ROWS_PER_G>(p, base, cnt);
        else
            run_rows<HO - (GROUPS - 1) * ROWS_PER_G>(p, base, cnt); // 14
    }
    __syncthreads();

    // Coalesced writeout: int -> float, float4 stores (whole plane overwritten).
    float4* __restrict__ o4 = (float4*)(out + (size_t)plane * PLANE);
#pragma unroll
    for (int i = 0; i < PLANE / 4 / BLOCK; ++i) {
        const int4 ci = c4[tid + i * BLOCK];
        o4[tid + i * BLOCK] =
            make_float4((float)ci.x, (float)ci.y, (float)ci.z, (float)ci.w);
    }
}

extern "C" void kernel_launch(void* const* d_in, const int* in_sizes, int n_in,
                              void* d_out, int out_size, void* d_ws, size_t ws_size,
                              hipStream_t stream) {
    const float* x = (const float*)d_in[0];
    float* out = (float*)d_out;
    energy_pool2d_kernel<<<NPLANES, BLOCK, 0, stream>>>(x, out);
}

// Round 4
// 32.215 us; speedup vs baseline: 2.0115x; 2.0115x over previous
//
#include <hip/hip_runtime.h>

// EnergyPool2d: N=16, C=64, H=W=128, 3x3 windows stride 1 -> Ho=Wo=126.
// +1 at first-argmax flat index, -1 at first-argmin flat index per window.
// R4: 4-wide x 2-tall window tiles; 8 windows share 4 rows loaded as float4
// pairs (1 vector-load-pair per row, all independent -> high MLP), then 8
// independent fully-unrolled 9-element first-occurrence scans in registers.

#define HH 128
#define WW 128
#define HO 126
#define WO 126
#define PLANE (HH * WW)   // 16384
#define NPLANES (16 * 64) // 1024
#define BLOCK 1024
#define CTILES 32         // col tiles: ct<31 -> 4 windows, ct=31 -> 2
#define RTILES 63         // row tiles: 2 window rows each (covers 126)
#define NTILES (CTILES * RTILES) // 2016

// First-occurrence argmax/argmin over a 3x3 window, row-major scan order
// (strict > / <), all offsets compile-time constants.
__device__ __forceinline__ void scan9(float w0, float w1, float w2,
                                      float w3, float w4, float w5,
                                      float w6, float w7, float w8,
                                      int base, int* __restrict__ cnt) {
    float vmax = w0, vmin = w0;
    int omax = 0, omin = 0;
#define STEP(v, off)                                      \
    do {                                                  \
        if ((v) > vmax) { vmax = (v); omax = (off); }     \
        if ((v) < vmin) { vmin = (v); omin = (off); }     \
    } while (0)
    STEP(w1, 1);
    STEP(w2, 2);
    STEP(w3, WW);
    STEP(w4, WW + 1);
    STEP(w5, WW + 2);
    STEP(w6, 2 * WW);
    STEP(w7, 2 * WW + 1);
    STEP(w8, 2 * WW + 2);
#undef STEP
    atomicAdd(&cnt[base + omax], 1);
    atomicAdd(&cnt[base + omin], -1);
}

__global__ __launch_bounds__(BLOCK, 8)
void energy_pool2d_kernel(const float* __restrict__ x, float* __restrict__ out) {
    __shared__ int cnt[PLANE]; // 64 KB

    const int tid = threadIdx.x;
    const int plane = blockIdx.x;
    const float* __restrict__ xp = x + (size_t)plane * PLANE;

    // Zero the LDS count plane.
    int4* c4 = (int4*)cnt;
#pragma unroll
    for (int i = 0; i < PLANE / 4 / BLOCK; ++i)
        c4[tid + i * BLOCK] = make_int4(0, 0, 0, 0);
    __syncthreads();

    for (int t = tid; t < NTILES; t += BLOCK) {
        const int rt = t >> 5;       // 0..62
        const int ct = t & 31;       // 0..31
        const int wr0 = rt * 2;      // first window row of tile (0..124)
        const int j0 = ct * 4;       // first window col of tile
        const float* __restrict__ p = xp + wr0 * WW + j0;

        // 4 input rows x 8 cols. Left float4 always; right float4 only for
        // ct<31 (ct=31 uses cols 124..127 only; also avoids OOB on the
        // final plane's last row).
        const float4 a0 = *(const float4*)(p);
        const float4 a1 = *(const float4*)(p + WW);
        const float4 a2 = *(const float4*)(p + 2 * WW);
        const float4 a3 = *(const float4*)(p + 3 * WW);
        float4 b0, b1, b2, b3;
        if (ct < CTILES - 1) {
            b0 = *(const float4*)(p + 4);
            b1 = *(const float4*)(p + WW + 4);
            b2 = *(const float4*)(p + 2 * WW + 4);
            b3 = *(const float4*)(p + 3 * WW + 4);
        } else {
            b0 = b1 = b2 = b3 = make_float4(0.f, 0.f, 0.f, 0.f);
        }
        const float r0[8] = {a0.x, a0.y, a0.z, a0.w, b0.x, b0.y, b0.z, b0.w};
        const float r1[8] = {a1.x, a1.y, a1.z, a1.w, b1.x, b1.y, b1.z, b1.w};
        const float r2[8] = {a2.x, a2.y, a2.z, a2.w, b2.x, b2.y, b2.z, b2.w};
        const float r3[8] = {a3.x, a3.y, a3.z, a3.w, b3.x, b3.y, b3.z, b3.w};

        const int nw = (ct < CTILES - 1) ? 4 : 2;
        const int base0 = wr0 * WW + j0;
#pragma unroll
        for (int c = 0; c < 4; ++c) {
            if (c < nw) {
                scan9(r0[c], r0[c + 1], r0[c + 2],
                      r1[c], r1[c + 1], r1[c + 2],
                      r2[c], r2[c + 1], r2[c + 2], base0 + c, cnt);
                scan9(r1[c], r1[c + 1], r1[c + 2],
                      r2[c], r2[c + 1], r2[c + 2],
                      r3[c], r3[c + 1], r3[c + 2], base0 + WW + c, cnt);
            }
        }
    }
    __syncthreads();

    // Coalesced writeout: int -> float, float4 stores (whole plane overwritten).
    float4* __restrict__ o4 = (float4*)(out + (size_t)plane * PLANE);
#pragma unroll
    for (int i = 0; i < PLANE / 4 / BLOCK; ++i) {
        const int4 ci = c4[tid + i * BLOCK];
        o4[tid + i * BLOCK] =
            make_float4((float)ci.x, (float)ci.y, (float)ci.z, (float)ci.w);
    }
}

extern "C" void kernel_launch(void* const* d_in, const int* in_sizes, int n_in,
                              void* d_out, int out_size, void* d_ws, size_t ws_size,
                              hipStream_t stream) {
    const float* x = (const float*)d_in[0];
    float* out = (float*)d_out;
    energy_pool2d_kernel<<<NPLANES, BLOCK, 0, stream>>>(x, out);
}